// Round 4
// baseline (795.173 us; speedup 1.0000x reference)
//
#include <hip/hip_runtime.h>
#include <math.h>

// Exactness: the FPS argmax chain and the knn/ball-query comparisons must be
// bitwise identical to the numpy reference. Disable FMA contraction globally;
// use explicit fmaf() where fusion is wanted (non-comparison math).
#pragma clang fp contract(off)

typedef float v2f __attribute__((ext_vector_type(2)));

// ---------------------------------------------------------------------------
// prep: point norms (exact ((x*x+y*y)+z*z) order) + weight transposes
// ---------------------------------------------------------------------------
__global__ __launch_bounds__(256) void prep_kernel(
    const float* __restrict__ xyz, const float* __restrict__ w0,
    const float* __restrict__ w1, const float* __restrict__ w2,
    float* __restrict__ norms, float* __restrict__ W0T,
    float* __restrict__ W1T, float* __restrict__ W2c)
{
    int t = blockIdx.x * 256 + threadIdx.x;
    if (t < 16384) {
        float x = xyz[t*3+0], y = xyz[t*3+1], z = xyz[t*3+2];
        norms[t] = (x*x + y*y) + z*z;          // matches np.sum(a*a,-1) order
        int c = t >> 7, k = t & 127;
        W1T[c*128 + k] = w1[k*128 + c];
    }
    if (t < 2432) { int c = t / 19, i = t - c*19; W0T[t] = w0[i*128 + c]; }
    if (t < 128)  { W2c[t] = w2[t*256]; }
}

// ---------------------------------------------------------------------------
// DPP helpers: 0xB1=xor1, 0x4E=xor2, 0x141=row_half_mirror, 0x140=row_mirror
// -> 16-lane-uniform; 0x142/0x143=row_bcast15/31 complete a 64-lane reduce
// (lane 63 holds the result). f64-KEY TRICK: for POSITIVE doubles IEEE order
// == integer bit order, so a (md2_bits<<32)|~p u64 key reinterpreted as f64
// reduces with ONE v_max_f64 per node (vs cmp_u64 + 2 cndmask). For keys with
// the high bit set (knn's sign-transformed ords) integer-MIN == f64-MAX over
// negative doubles, and excluded entries (0xFFFFFFFF hi) are quiet NaNs that
// v_max_f64 drops. Denormals compare exactly (no f64 FTZ on CDNA).
// ---------------------------------------------------------------------------
template<int CTRL>
__device__ __forceinline__ double dpp_f64(double v) {
    int lo = __double2loint(v), hi = __double2hiint(v);
    int plo = __builtin_amdgcn_update_dpp(lo, lo, CTRL, 0xF, 0xF, false);
    int phi = __builtin_amdgcn_update_dpp(hi, hi, CTRL, 0xF, 0xF, false);
    return __hiloint2double(phi, plo);
}
template<int CTRL>
__device__ __forceinline__ double max_f64_dpp(double k) {
    return fmax(dpp_f64<CTRL>(k), k);   // unwritten lanes get self -> no-op
}
#define KD(md2bits_f, ipi) __hiloint2double(__float_as_int(md2bits_f), (int)(ipi))

// ---------------------------------------------------------------------------
// fused FPS + KDE — round-18: round-16 FPS core (4 active waves, 16 pts/lane,
// f64-max keys, single barrier) with two deltas vs round-17:
//  - spinner tail REMOVED (round-3 evidence: 95% VALUBusy, fps +11us -> DPM
//    clock theory refuted; spinners only added issue contention)
//  - LDS padded to ~82KB -> 1 block/CU. At 78KB, a KDE block co-resides on
//    each FPS CU for the first ~50us and steals issue slots from the FPS
//    waves (2 waves/SIMD during ~100 iterations). KDE itself is issue-bound,
//    not occupancy-bound: 8 waves at 1 block/CU still fill all 4 SIMDs, and
//    the KDE phase stays fully hidden under the 550us FPS tail.
// ---------------------------------------------------------------------------
__global__ __launch_bounds__(512) void fps_kde_kernel(
    const float* __restrict__ xyz, const float* __restrict__ norms,
    float* __restrict__ new_xyz, float* __restrict__ invden)
{
    __shared__ float4 pts[4096];                 // 64KB
    __shared__ float  nxb[3072];                 // 12KB FPS output staging
    __shared__ __attribute__((aligned(16))) double swkd[2][4];
    __shared__ float lds_pad[1024];              // 4KB: force 1 block/CU
    int tid = threadIdx.x;
    if (tid == 0x7fffffff) lds_pad[0] = 0.0f;    // keep pad alive, never runs

    if (blockIdx.x < 4) {
        // ------------------------------ FPS ------------------------------
        int b = blockIdx.x;
        const float* Xb = xyz + b*12288;
        for (int t = tid; t < 4096; t += 512)
            pts[t] = make_float4(Xb[t*3+0], Xb[t*3+1], Xb[t*3+2], 0.0f);
        __syncthreads();
        if (tid < 256) {
            int lane = tid & 63, wave = tid >> 6;
            v2f Xp[8], Yp[8], Zp[8], md2[8];
            unsigned ip[16];
#pragma unroll
            for (int k = 0; k < 8; ++k) {
                float4 A = pts[(2*k)*256 + tid];
                float4 B = pts[(2*k+1)*256 + tid];
                Xp[k].x = A.x;  Xp[k].y = B.x;
                Yp[k].x = A.y;  Yp[k].y = B.y;
                Zp[k].x = A.z;  Zp[k].y = B.z;
                md2[k].x = INFINITY; md2[k].y = INFINITY;
                ip[2*k]   = ~((unsigned)((2*k)*256 + tid));
                ip[2*k+1] = ~((unsigned)((2*k+1)*256 + tid));
            }
            float cx = pts[0].x, cy = pts[0].y, cz = pts[0].z;
            if (tid == 0) { nxb[0] = cx; nxb[1] = cy; nxb[2] = cz; }
            int buf = 0;
            for (int it = 1; it < 1024; ++it) {
                v2f cx2, cy2, cz2;
                cx2.x = cx; cx2.y = cx;
                cy2.x = cy; cy2.y = cy;
                cz2.x = cz; cz2.y = cz;
#pragma unroll
                for (int k = 0; k < 8; ++k) {
                    v2f dx = Xp[k] - cx2, dy = Yp[k] - cy2, dz = Zp[k] - cz2;
                    v2f dd = (dx*dx + dy*dy) + dz*dz;   // unfused (contract off)
                    md2[k] = __builtin_elementwise_min(md2[k], dd); // v_pk_min
                }
                // 16 f64 keys, 15-node fmax tree (all keys positive doubles)
                double t0 = fmax(fmax(KD(md2[0].x,ip[0]),  KD(md2[0].y,ip[1])),
                                 fmax(KD(md2[1].x,ip[2]),  KD(md2[1].y,ip[3])));
                double t1 = fmax(fmax(KD(md2[2].x,ip[4]),  KD(md2[2].y,ip[5])),
                                 fmax(KD(md2[3].x,ip[6]),  KD(md2[3].y,ip[7])));
                double t2 = fmax(fmax(KD(md2[4].x,ip[8]),  KD(md2[4].y,ip[9])),
                                 fmax(KD(md2[5].x,ip[10]), KD(md2[5].y,ip[11])));
                double t3 = fmax(fmax(KD(md2[6].x,ip[12]), KD(md2[6].y,ip[13])),
                                 fmax(KD(md2[7].x,ip[14]), KD(md2[7].y,ip[15])));
                double key = fmax(fmax(t0, t1), fmax(t2, t3));
                // 6-step f64 DPP chain -> lane 63 holds this wave's winner
                key = max_f64_dpp<0xB1>(key);
                key = max_f64_dpp<0x4E>(key);
                key = max_f64_dpp<0x141>(key);
                key = max_f64_dpp<0x140>(key);
                key = max_f64_dpp<0x142>(key);
                key = max_f64_dpp<0x143>(key);
                if (lane == 63) swkd[buf][wave] = key;   // 4 slots
                __syncthreads();                 // single barrier (dbuf'd slots)
                // all lanes: 4 wave winners via two aligned b128, 3 fmax
                double2 wab = *((const double2*)&swkd[buf][0]);
                double2 wcd = *((const double2*)&swkd[buf][2]);
                double kk = fmax(fmax(wab.x, wab.y), fmax(wcd.x, wcd.y));
                int fp = (int)(~((unsigned)__double2loint(kk)));
                float4 c = pts[fp];              // broadcast read
                cx = c.x; cy = c.y; cz = c.z;
                if (tid == 0) { nxb[it*3+0] = cx; nxb[it*3+1] = cy; nxb[it*3+2] = cz; }
                buf ^= 1;
            }
        } else {
            // idle waves: match the active waves' barrier count, issue nothing
            for (int it = 1; it < 1024; ++it) __syncthreads();
        }
        __syncthreads();
        float* NX = new_xyz + b*3072;
        for (int t = tid; t < 3072; t += 512) NX[t] = nxb[t];
    } else {
        // ------------------------------ KDE ------------------------------
        // In-ball count ~17 << KDE_K=128, so the reference's top-128 +
        // padding + correction reduces exactly to the mean of mvn over all
        // in-ball neighbors. Membership test uses the pdist2 expansion
        // formula (unfused) to match the reference set bitwise.
        int idx = blockIdx.x - 4;
        int b = idx >> 9;                    // 512 blocks per batch
        int wave = tid >> 6, lane = tid & 63;
        int i_local = ((idx & 511) << 3) + wave;
        const float* Xb = xyz + b*12288;
        const float* Nb = norms + b*4096;
        for (int t = tid; t < 4096; t += 512)
            pts[t] = make_float4(Xb[t*3+0], Xb[t*3+1], Xb[t*3+2], Nb[t]);
        __syncthreads();
        float4 c = pts[i_local];
        const float Rv    = sqrtf(0.05f);
        const float inv_s = 1.0f / (Rv*Rv);
        const float K1    = -3.0f*logf(Rv) - 1.5f*logf(2.0f*3.1415926f);
        float csum = 0.0f; int cnt = 0;
        for (int j = lane; j < 4096; j += 64) {
            float4 q = pts[j];
            float dot = (c.x*q.x + c.y*q.y) + c.z*q.z;
            float t2 = 2.0f * dot;
            float d2 = (c.w + q.w) - t2;
            if (d2 < 0.01f) {                // 0.01f == float32(0.1*0.1)
                float gx = q.x - c.x, gy = q.y - c.y, gz = q.z - c.z;
                float dd = (gx*gx + gy*gy) + gz*gz;
                csum += expf(-0.5f * (dd * inv_s) + K1);
                cnt  += 1;
            }
        }
#pragma unroll
        for (int m = 1; m < 64; m <<= 1) {
            csum += __shfl_xor(csum, m, 64);
            cnt  += __shfl_xor(cnt,  m, 64);
        }
        if (lane == 0) {
            float den = csum / (float)cnt;
            invden[b*4096 + i_local] = 1.0f / den;
        }
    }
}

// ---------------------------------------------------------------------------
// KNN: one wave per query, barrier-free, LDS slice per wave with
// sign-transformed u32 ords (unsigned order == float order; excluded =
// 0xFFFFFFFF). 32 rounds of stable lex-min (ord, j) via the f64-max trick
// (all keys negative doubles; excluded = quiet NaN dropped by fmax).
// ---------------------------------------------------------------------------
__global__ __launch_bounds__(256) void knn_kernel(
    const float* __restrict__ xyz, const float* __restrict__ norms,
    const float* __restrict__ new_xyz, int* __restrict__ knn_idx)
{
    __shared__ unsigned sd2[4*4096];  // 64KB
    __shared__ int sIdx[4*32];
    int wave = threadIdx.x >> 6, lane = threadIdx.x & 63;
    int qg = blockIdx.x*4 + wave;  // global query id = b*1024 + q
    int b = qg >> 10;
    const float* Q = new_xyz + qg*3;
    float qx = Q[0], qy = Q[1], qz = Q[2];
    float nq = (qx*qx + qy*qy) + qz*qz;
    const float* Xb = xyz + b*12288;
    const float* Nb = norms + b*4096;
    unsigned* d2w = sd2 + wave*4096;
    for (int j = lane; j < 4096; j += 64) {
        float x = Xb[j*3+0], y = Xb[j*3+1], z = Xb[j*3+2];
        float dot = (qx*x + qy*y) + qz*z;
        float t2 = 2.0f*dot;
        float d = (nq + Nb[j]) - t2;
        unsigned u = __float_as_uint(d);
        unsigned m = ((unsigned)((int)u >> 31)) | 0x80000000u;
        d2w[j] = u ^ m;
    }
    for (int r = 0; r < 32; ++r) {
        // 4 independent fmax accumulators over (ord, j) f64 keys
        double a0 = -INFINITY, a1 = -INFINITY, a2 = -INFINITY, a3 = -INFINITY;
#pragma unroll
        for (int t = 0; t < 16; ++t) {
            int jb = t*256 + lane*4;
            uint4 v = *((const uint4*)(d2w + jb));
            a0 = fmax(a0, __hiloint2double((int)v.x, jb));
            a1 = fmax(a1, __hiloint2double((int)v.y, jb+1));
            a2 = fmax(a2, __hiloint2double((int)v.z, jb+2));
            a3 = fmax(a3, __hiloint2double((int)v.w, jb+3));
        }
        double key = fmax(fmax(a0, a1), fmax(a2, a3));
        key = max_f64_dpp<0xB1>(key);
        key = max_f64_dpp<0x4E>(key);
        key = max_f64_dpp<0x141>(key);
        key = max_f64_dpp<0x140>(key);
        key = max_f64_dpp<0x142>(key);
        key = max_f64_dpp<0x143>(key);   // lane 63 holds wave winner
        int jwin = __builtin_amdgcn_readlane(__double2loint(key), 63);
        if (lane == 0) { sIdx[wave*32 + r] = jwin; d2w[jwin] = 0xFFFFFFFFu; }
    }
    if (lane < 32) knn_idx[qg*32 + lane] = sIdx[wave*32 + lane];
}

// ---------------------------------------------------------------------------
// Grouped MLP: thread per (b,p,k) row; chain 19->128->128->1 (only channel 0
// of mlp2 is consumed). W1T (64KB) staged in LDS (round-17, kept: L1 weight
// reads are wave-uniform LDS broadcasts). Round-18: final_kernel FUSED as an
// epilogue — pw goes to a 1KB LDS buffer instead of global ptsw; each thread
// then owns output column f=tid and computes 8 rows with the wnp column held
// in registers. Identical fma order (w ascending, seeded 0) -> bitwise exact.
// Kills one launch + the 512KB ptsw global round-trip.
// ---------------------------------------------------------------------------
__global__ __launch_bounds__(256, 2) void group_mlp_kernel(
    const float* __restrict__ xyz, const float* __restrict__ feat,
    const float* __restrict__ new_xyz, const int* __restrict__ knn_idx,
    const float* __restrict__ invden,
    const float* __restrict__ W0T, const float* __restrict__ W1T,
    const float* __restrict__ W2c, const float* __restrict__ wwn,
    const float* __restrict__ wnl0, const float* __restrict__ wnl1,
    const float* __restrict__ wnp, float* __restrict__ out)
{
    __shared__ float sW1[16384];   // 64KB staged W1T
    __shared__ float sPW[8][33];   // pw staging, +1 pad (k==0 write banks)
    // stage W1T: 16 coalesced float4 loads/thread -> LDS (latency hidden
    // under the L0 block below; barrier is after L0)
    {
        const float4* g4 = (const float4*)W1T;
        float4* s4 = (float4*)sW1;
#pragma unroll
        for (int i = 0; i < 16; ++i)
            s4[i*256 + threadIdx.x] = g4[i*256 + threadIdx.x];
    }

    int row = blockIdx.x*256 + threadIdx.x;   // 131072 rows
    int k  = row & 31;
    int pg = row >> 5;                         // b*1024+p
    int b  = row >> 15;
    int j  = knn_idx[row];
    const float* Xb = xyz + b*12288;
    const float* Q  = new_xyz + pg*3;
    float in[19];
    in[0] = Xb[j*3+0] - Q[0];
    in[1] = Xb[j*3+1] - Q[1];
    in[2] = Xb[j*3+2] - Q[2];
    const float4* F = (const float4*)(feat + (size_t)(b*4096 + j)*16);
    float4 f0 = F[0], f1 = F[1], f2 = F[2], f3 = F[3];
    in[3]=f0.x; in[4]=f0.y; in[5]=f0.z; in[6]=f0.w;
    in[7]=f1.x; in[8]=f1.y; in[9]=f1.z; in[10]=f1.w;
    in[11]=f2.x; in[12]=f2.y; in[13]=f2.z; in[14]=f2.w;
    in[15]=f3.x; in[16]=f3.y; in[17]=f3.z; in[18]=f3.w;

    // density scale: gd / max_k(gd), then 1->16->1 relu MLP
    float gd = invden[b*4096 + j];
    float mx = gd;
#pragma unroll
    for (int m = 1; m < 32; m <<= 1) mx = fmaxf(mx, __shfl_xor(mx, m, 64));
    float dsc = gd / mx;
    float sacc = 0.0f;
#pragma unroll
    for (int t = 0; t < 16; ++t)
        sacc = fmaf(fmaxf(dsc * wnl0[t], 0.0f), wnl1[t], sacc);
    float ds = fmaxf(sacc, 0.0f);

    // L0: 19 -> 128 (fully unrolled so h1 stays in registers)
    float h1[128];
#pragma unroll
    for (int c = 0; c < 128; ++c) {
        const float* w = W0T + c*19;
        float a = in[0]*w[0];
#pragma unroll
        for (int i = 1; i < 19; ++i) a = fmaf(in[i], w[i], a);
        h1[c] = fmaxf(a, 0.0f);
    }
    __syncthreads();   // staging complete (hidden under L0)

    // L1 + L2(col 0): weights from LDS, wave-uniform broadcast b128 reads.
    // Accumulation order identical to the global-memory version.
    float acc0 = 0.0f;
    for (int c2 = 0; c2 < 128; ++c2) {
        const float4* w4 = (const float4*)(sW1 + c2*128);
        float a0 = 0.0f, a1 = 0.0f, a2 = 0.0f, a3 = 0.0f;
#pragma unroll
        for (int kk = 0; kk < 32; ++kk) {
            float4 wv = w4[kk];
            a0 = fmaf(h1[4*kk+0], wv.x, a0);
            a1 = fmaf(h1[4*kk+1], wv.y, a1);
            a2 = fmaf(h1[4*kk+2], wv.z, a2);
            a3 = fmaf(h1[4*kk+3], wv.w, a3);
        }
        float a = (a0+a1) + (a2+a3);
        acc0 = fmaf(fmaxf(a, 0.0f), W2c[c2], acc0);
    }
    float h0 = fmaxf(acc0, 0.0f);
    float s = h0 * ds;

    // weight net (3->32) + reduce over k (32 lanes of half-wave) -> LDS
    float gx = in[0], gy = in[1], gz = in[2];
    int l = threadIdx.x >> 5;                  // local pg index 0..7
#pragma unroll
    for (int w = 0; w < 32; ++w) {
        float a = gx * wwn[w];
        a = fmaf(gy, wwn[32+w], a);
        a = fmaf(gz, wwn[64+w], a);
        float part = s * fmaxf(a, 0.0f);
#pragma unroll
        for (int m = 1; m < 32; m <<= 1) part += __shfl_xor(part, m, 64);
        if (k == 0) sPW[l][w] = part;
    }
    __syncthreads();

    // fused final: thread f=tid owns output column f for the block's 8 rows.
    // wnp column f held in 32 registers (coalesced loads, one latency window).
    int f = threadIdx.x;
    float wc[32];
#pragma unroll
    for (int w = 0; w < 32; ++w) wc[w] = wnp[w*256 + f];
    int pg0 = blockIdx.x * 8;
#pragma unroll
    for (int r = 0; r < 8; ++r) {
        float a = 0.0f;
#pragma unroll
        for (int w = 0; w < 32; ++w) a = fmaf(sPW[r][w], wc[w], a);
        out[(pg0 + r)*256 + f] = fmaxf(a, 0.0f);
    }
}

// ---------------------------------------------------------------------------
extern "C" void kernel_launch(void* const* d_in, const int* in_sizes, int n_in,
                              void* d_out, int out_size, void* d_ws, size_t ws_size,
                              hipStream_t stream) {
    const float* xyz  = (const float*)d_in[0];
    const float* feat = (const float*)d_in[1];
    const float* w0   = (const float*)d_in[2];
    const float* w1   = (const float*)d_in[3];
    const float* w2   = (const float*)d_in[4];
    const float* wwn  = (const float*)d_in[5];
    const float* wnl0 = (const float*)d_in[6];
    const float* wnl1 = (const float*)d_in[7];
    const float* wnp  = (const float*)d_in[8];

    float* out_all  = (float*)d_out;
    float* new_xyz  = out_all;            // 4*1024*3 = 12288 floats
    float* out2     = out_all + 12288;    // 4*1024*256 floats

    char* ws = (char*)d_ws;
    float* norms  = (float*)(ws + 0);        // 16384 f  (64KB)
    float* invden = (float*)(ws + 65536);    // 16384 f  (64KB)
    int*   knn    = (int*)  (ws + 131072);   // 131072 i (512KB)
    float* W0T    = (float*)(ws + 655360);   // 2432 f
    float* W1T    = (float*)(ws + 665088);   // 16384 f
    float* W2c    = (float*)(ws + 730624);   // 128 f

    prep_kernel<<<64, 256, 0, stream>>>(xyz, w0, w1, w2, norms, W0T, W1T, W2c);
    fps_kde_kernel<<<2052, 512, 0, stream>>>(xyz, norms, new_xyz, invden);
    knn_kernel<<<1024, 256, 0, stream>>>(xyz, norms, new_xyz, knn);
    group_mlp_kernel<<<512, 256, 0, stream>>>(xyz, feat, new_xyz, knn, invden,
                                              W0T, W1T, W2c, wwn, wnl0, wnl1,
                                              wnp, out2);
}